// Round 7
// baseline (214.536 us; speedup 1.0000x reference)
//
#include <hip/hip_runtime.h>

// Path signature M=4, d=10, L=256, B=2048.
// Thread owns (batch b, pair (i,j), k-half h): s1,s2, s3[5], s4[5][10].
// h is WAVE-UNIFORM (h = wave_id & 1) -> two template<K0> copies, no divergence.
//
// ROUND-7: kill the AGPR spill traffic at the constraint level. Rounds 4-6
// showed the allocator parks ~half the accumulator in AGPRs and pays
// v_accvgpr_read/write around every FMA (~130 VALU insts/step vs ~73 useful;
// VGPR_Count 48-68 << ~85 live floats, zero scratch). Occupancy attributes
// didn't change its mind. Now every s3/s4 update is an inline-asm
// v_fma/v_fmac with "+v" operands: the value must be in an ARCH VGPR at the
// use, so AGPR residency costs exactly the copies it already pays -> the
// allocator's cheapest choice is VGPR residency. waves_per_eu(3,3) keeps the
// budget at 170.
// Also: LDS rows padded to 12 floats (48B) so the v-row load is
// ds_read_b128 x2 + b64 (3 LDS insts) instead of 5x b64 — halves LDS pipe time.

#define D      10
#define DPAD   12
#define LPATH  256
#define NSTEP  255
#define SIGTOT 11110
#define TB     256
#define SLOTS  3
#define SLOTF  (NSTEP * DPAD)   // 3060 floats per batch slot

template<int K0>
__device__ __forceinline__ void run_steps(const float* __restrict__ vrow,
                                          int i, int j,
                                          float& s1, float& s2,
                                          float (&s3)[5], float (&s4)[50]) {
    #pragma unroll 1
    for (int t = 0; t < NSTEP; ++t) {
        const float* row = vrow + t * DPAD;
        const float4 v03 = *(const float4*)(row);
        const float4 v47 = *(const float4*)(row + 4);
        const float2 v89 = *(const float2*)(row + 8);
        const float v[10] = {v03.x, v03.y, v03.z, v03.w,
                             v47.x, v47.y, v47.z, v47.w,
                             v89.x, v89.y};
        const float vi = row[i];            // LDS scalar read
        const float vj = row[j];
        const float b_ = vj * (vi * (1.f/24.f) + s1 * (1.f/6.f)) + s2 * 0.5f;
        const float a_ = vj * (vi * (1.f/6.f)  + s1 * 0.5f)      + s2;
        s2 += vj * fmaf(vi, 0.5f, s1);      // old s1
        s1 += vi;
        float c[5];
        #pragma unroll
        for (int k = 0; k < 5; ++k) {
            const float vk = v[K0 + k];     // compile-time index
            // c[k] = b_*vk + s3_old ; s3 = a_*vk + s3_old  (dataflow on s3_old)
            asm("v_fma_f32 %0, %1, %2, %3" : "=v"(c[k]) : "v"(b_), "v"(vk), "v"(s3[k]));
            asm("v_fmac_f32 %0, %1, %2" : "+v"(s3[k]) : "v"(a_), "v"(vk));
        }
        #pragma unroll
        for (int k = 0; k < 5; ++k) {
            #pragma unroll
            for (int l = 0; l < D; ++l)
                asm("v_fmac_f32 %0, %1, %2" : "+v"(s4[k * 10 + l]) : "v"(c[k]), "v"(v[l]));
        }
    }
}

__attribute__((amdgpu_waves_per_eu(3, 3)))
__global__ __launch_bounds__(TB)
void sig_kernel(const float* __restrict__ x, float* __restrict__ out, int B) {
    __shared__ float vlds[SLOTS * SLOTF];   // 36720 B
    const int tid = threadIdx.x;
    const int blk = blockIdx.x;
    const int q0  = blk * (TB / 2);          // first pair index of this block
    const int b0  = q0 / 100;                // first batch touched
    const int bL  = (q0 + TB / 2 - 1) / 100; // last batch touched
    const int nslot = bL - b0 + 1;           // 2 or 3

    // stage increments v[t][dim] into padded rows (pad lanes never read)
    for (int e = tid; e < nslot * (NSTEP * D); e += TB) {
        const int s   = e / (NSTEP * D);
        const int r   = e - s * (NSTEP * D);
        const int trow = r / D;
        const int dim  = r - trow * D;
        const int bb = b0 + s;
        float v = 0.f;
        if (bb < B) {
            const float* bx = x + (size_t)bb * (LPATH * D);
            v = bx[r + D] - bx[r];
        }
        vlds[s * SLOTF + trow * DPAD + dim] = v;
    }
    __syncthreads();

    // wave-uniform half assignment: global wave w -> h = w&1; lane carries pair
    const int wg   = blk * (TB / 64) + (tid >> 6);   // global wave id
    const int lane = tid & 63;
    const int h    = wg & 1;                          // wave-uniform
    const int q    = (wg >> 1) * 64 + lane;           // pair index
    const int b    = q / 100;
    const int p    = q - b * 100;
    const int i    = p / 10;
    const int j    = p - i * 10;
    const float* vrow = vlds + (b - b0) * SLOTF;

    float s1 = 0.f, s2 = 0.f;
    float s3[5], s4[50];
    #pragma unroll
    for (int k = 0; k < 5; ++k) s3[k] = 0.f;
    #pragma unroll
    for (int k = 0; k < 50; ++k) s4[k] = 0.f;

    if (h == 0) run_steps<0>(vrow, i, j, s1, s2, s3, s4);
    else        run_steps<5>(vrow, i, j, s1, s2, s3, s4);

    // epilogue: [S1(10) | S2(100) | S3(1000) | S4(10000)] per batch
    const size_t ob = (size_t)b * SIGTOT;
    const int K0 = 5 * h;
    if (h == 0) {
        if (j == 0) out[ob + i] = s1;
        out[ob + 10 + p] = s2;
    }
    float* o3 = out + ob + 110 + (size_t)p * 10 + K0;
    #pragma unroll
    for (int k = 0; k < 5; ++k) o3[k] = s3[k];
    float* o4 = out + ob + 1110 + (size_t)p * 100 + (size_t)K0 * 10;
    #pragma unroll
    for (int k = 0; k < 5; ++k) {
        #pragma unroll
        for (int lp = 0; lp < 5; ++lp) {
            *(float2*)(o4 + k * 10 + 2 * lp) =
                make_float2(s4[k * 10 + 2 * lp], s4[k * 10 + 2 * lp + 1]);
        }
    }
}

extern "C" void kernel_launch(void* const* d_in, const int* in_sizes, int n_in,
                              void* d_out, int out_size, void* d_ws, size_t ws_size,
                              hipStream_t stream) {
    const float* x = (const float*)d_in[0];
    float* out = (float*)d_out;
    const int B = in_sizes[0] / (LPATH * D);        // 2048
    const int nthreads = B * 100 * 2;               // 409600
    const int nblocks = nthreads / TB;              // 1600
    sig_kernel<<<nblocks, TB, 0, stream>>>(x, out, B);
}

// Round 8
// 149.175 us; speedup vs baseline: 1.4381x; 1.4381x over previous
//
#include <hip/hip_runtime.h>

// Path signature M=4, d=10, L=256, B=2048 — MFMA reformulation.
//
// Unrolled recurrence with closed-form prefix/suffix sums:
//   S1_t = x_t - x_0 (old S1 at step t),  R_t = x_255 - x_{t+1} (suffix sum of v)
//   a_t[ij] = v_i v_j/6  + S1_t[i] v_j/2 + S2_t[ij]
//   b_t[ij] = v_i v_j/24 + S1_t[i] v_j/6 + S2_t[ij]/2
//   S2_{t+1} = S2_t + v_j (v_i/2 + S1_t[i])           (sequential, tiny)
//   S3[ij,k]  = sum_t a_t[ij] v_t[k]
//   S4[ij,kl] = sum_t b_t[ij] (v_t[k] v_t[l]) + a_t[ij] (v_t[k] R_t[l])
// => C[m=ij, n] = P^T Q, K-rows per t: [a_hi, a_lo, b_hi, b_lo] (bf16 split for
// accuracy) paired with Q rows [u, u, w, w]; Q cols 100..109 hold v_t (paired
// with a rows, 0 with b rows) so S3 falls out of the same GEMM. K = 4*256 = 1024.
// One workgroup (256 thr) per batch; 32 chunks of K=32 (8 t's); producer phase
// (threads 0..109: S2 recurrence + bf16 pack to LDS) alternates with consumer
// phase (4 waves x 16 MFMA tiles of 16x16x32 covering 128x128 padded C).
// S1, S2 written exact fp32. LDS 30.7KB -> 5 wg/CU.

#define NT     255
#define SIG    11110
#define TPC    8          // t's per chunk
#define NCH    32         // chunks (256 t-slots, slot 255 zeroed)
#define RSW    20         // P/Q row stride in u32 words (80B: 16B-aligned, low-conflict)
#define MROWS  128

typedef short bf16x8 __attribute__((ext_vector_type(8)));
typedef float f32x4  __attribute__((ext_vector_type(4)));

static __device__ __forceinline__ unsigned int f2bf_bits(float f) {
    unsigned int u = __float_as_uint(f);
    return ((u + 0x7FFFu + ((u >> 16) & 1u)) >> 16) & 0xFFFFu;  // RNE bf16
}

__global__ __launch_bounds__(256, 2)
void sig_mfma_kernel(const float* __restrict__ xg, float* __restrict__ out) {
    __shared__ float        xs[256 * 10];        // 10240 B: path rows
    __shared__ unsigned int Pl[MROWS * RSW];     // 10240 B: A matrix [M=pair][K] bf16-pairs
    __shared__ unsigned int Ql[MROWS * RSW];     // 10240 B: B matrix [N=cell][K]

    const int tid  = threadIdx.x;
    const int b    = blockIdx.x;
    const int lane = tid & 63;
    const int wave = tid >> 6;

    // stage x (coalesced, linear)
    const float* xb = xg + (size_t)b * 2560;
    #pragma unroll
    for (int r = 0; r < 10; ++r) xs[r * 256 + tid] = xb[r * 256 + tid];

    // zero pad rows once: P rows 100..127, Q rows 110..127 (K words 0..15)
    for (int e = tid; e < 448; e += 256) Pl[(100 + e / 16) * RSW + (e % 16)] = 0;
    for (int e = tid; e < 288; e += 256) Ql[(110 + e / 16) * RSW + (e % 16)] = 0;
    __syncthreads();

    // producer state
    int i = 0, j = 0;
    float x0i = 0, xti = 0, xtj = 0, xLj = 0, s2 = 0, xc = 0;
    if (tid < 100) {
        i = tid / 10; j = tid - i * 10;
        x0i = xs[i]; xti = x0i; xtj = xs[j]; xLj = xs[2550 + j];
    } else if (tid < 110) {
        xc = xs[tid - 100];
    }

    f32x4 acc[4][4];
    #pragma unroll
    for (int mi = 0; mi < 4; ++mi)
        #pragma unroll
        for (int ni = 0; ni < 4; ++ni) acc[mi][ni] = (f32x4){0.f, 0.f, 0.f, 0.f};

    const int r0 = (wave & 1) * 64;    // this wave's C row base
    const int c0 = (wave >> 1) * 64;   // this wave's C col base

    for (int ch = 0; ch < NCH; ++ch) {
        // ---------- producer phase ----------
        if (tid < 100) {
            #pragma unroll
            for (int tl = 0; tl < TPC; ++tl) {
                const int  t     = ch * TPC + tl;
                const bool valid = (t < NT);
                const int  tt    = valid ? t : (NT - 1);
                const float xt1i = xs[(tt + 1) * 10 + i];
                const float xt1j = xs[(tt + 1) * 10 + j];
                const float vi = xt1i - xti, vj = xt1j - xtj;
                const float s1f  = xti - x0i;
                const float vivj = vi * vj;
                const float t1   = s1f * vj;
                float a  = fmaf(vivj, 1.f/6.f,  fmaf(t1, 0.5f,     s2));
                float bb = fmaf(vivj, 1.f/24.f, fmaf(t1, 1.f/6.f,  0.5f * s2));
                float u  = vi * (xLj - xt1j);   // v_k * R_t[l]
                float w  = vivj;                // v_k * v_l
                if (!valid) { a = 0.f; bb = 0.f; u = 0.f; w = 0.f; }
                const unsigned int ah = f2bf_bits(a);
                const unsigned int pa = ah | (f2bf_bits(a - __uint_as_float(ah << 16)) << 16);
                const unsigned int bh = f2bf_bits(bb);
                const unsigned int pb = bh | (f2bf_bits(bb - __uint_as_float(bh << 16)) << 16);
                const unsigned int ub = f2bf_bits(u), wb = f2bf_bits(w);
                *(uint2*)&Pl[tid * RSW + tl * 2] = make_uint2(pa, pb);
                *(uint2*)&Ql[tid * RSW + tl * 2] = make_uint2(ub | (ub << 16), wb | (wb << 16));
                if (valid) {
                    s2 = fmaf(vj, fmaf(vi, 0.5f, s1f), s2);
                    xti = xt1i; xtj = xt1j;
                }
            }
        } else if (tid < 110) {
            const int cdim = tid - 100;          // Q cols 100..109: v_t (S3 via GEMM)
            #pragma unroll
            for (int tl = 0; tl < TPC; ++tl) {
                const int  t     = ch * TPC + tl;
                const bool valid = (t < NT);
                const int  tt    = valid ? t : (NT - 1);
                const float xn = xs[(tt + 1) * 10 + cdim];
                const float v  = valid ? (xn - xc) : 0.f;
                const unsigned int vb = f2bf_bits(v);
                *(uint2*)&Ql[(100 + cdim) * RSW + tl * 2] = make_uint2(vb | (vb << 16), 0u);
                if (valid) xc = xn;
            }
        }
        __syncthreads();
        // ---------- consumer phase: 16 MFMA tiles per wave ----------
        bf16x8 Bf[4];
        #pragma unroll
        for (int ni = 0; ni < 4; ++ni)
            Bf[ni] = *(const bf16x8*)((const char*)Ql +
                     (size_t)(c0 + ni * 16 + (lane & 15)) * 80 + (lane >> 4) * 16);
        #pragma unroll
        for (int mi = 0; mi < 4; ++mi) {
            const bf16x8 Af = *(const bf16x8*)((const char*)Pl +
                     (size_t)(r0 + mi * 16 + (lane & 15)) * 80 + (lane >> 4) * 16);
            #pragma unroll
            for (int ni = 0; ni < 4; ++ni)
                acc[mi][ni] = __builtin_amdgcn_mfma_f32_16x16x32_bf16(Af, Bf[ni], acc[mi][ni], 0, 0, 0);
        }
        __syncthreads();
    }

    // ---------- epilogue ----------
    const size_t base = (size_t)b * SIG;
    if (tid < 10)  out[base + tid] = xs[2550 + tid] - xs[tid];   // S1 exact
    if (tid < 100) out[base + 10 + tid] = s2;                    // S2 exact
    // C/D layout (m89-verified): col = lane&15, row = (lane>>4)*4 + reg
    #pragma unroll
    for (int mi = 0; mi < 4; ++mi) {
        #pragma unroll
        for (int ni = 0; ni < 4; ++ni) {
            #pragma unroll
            for (int r = 0; r < 4; ++r) {
                const int m = r0 + mi * 16 + (lane >> 4) * 4 + r;
                const int n = c0 + ni * 16 + (lane & 15);
                if (m < 100) {
                    if (n < 100)      out[base + 1110 + m * 100 + n]        = acc[mi][ni][r]; // S4
                    else if (n < 110) out[base + 110  + m * 10  + (n - 100)] = acc[mi][ni][r]; // S3
                }
            }
        }
    }
}

extern "C" void kernel_launch(void* const* d_in, const int* in_sizes, int n_in,
                              void* d_out, int out_size, void* d_ws, size_t ws_size,
                              hipStream_t stream) {
    const float* x = (const float*)d_in[0];
    float* out = (float*)d_out;
    const int B = in_sizes[0] / 2560;   // 2048 batches, one workgroup each
    sig_mfma_kernel<<<B, 256, 0, stream>>>(x, out);
}